// Round 1
// 587.034 us; speedup vs baseline: 1.0148x; 1.0148x over previous
//
#include <hip/hip_runtime.h>

#define N_FEAT 128
#define F1 16
#define F2 2
#define SCAN_CHUNK 2048
#define XPAD 132

// ---------------- degree of dst (no self loop yet) ----------------
__global__ void deg_kernel(const int* __restrict__ col, int E, int* __restrict__ deg) {
    int i = blockIdx.x * blockDim.x + threadIdx.x;
    int e0 = i * 4;
    if (e0 + 3 < E) {
        int4 c = *(const int4*)(col + e0);
        atomicAdd(&deg[c.x], 1); atomicAdd(&deg[c.y], 1);
        atomicAdd(&deg[c.z], 1); atomicAdd(&deg[c.w], 1);
    } else {
        for (int e = e0; e < E; ++e) atomicAdd(&deg[col[e]], 1);
    }
}

// ---------------- hierarchical exclusive scan of deg -> start ----------------
__global__ __launch_bounds__(256) void scan_blocks_kernel(const int* __restrict__ deg,
        int* __restrict__ start, int* __restrict__ bsum, int N) {
    __shared__ int wsum[4];
    int t = threadIdx.x;
    int base = blockIdx.x * SCAN_CHUNK + t * 8;
    int v[8], ex[8];
    int tl = 0;
#pragma unroll
    for (int u = 0; u < 8; ++u) {
        int idx = base + u;
        v[u] = (idx < N) ? deg[idx] : 0;
        ex[u] = tl; tl += v[u];
    }
    int lane = t & 63, w = t >> 6;
    int sum = tl;
#pragma unroll
    for (int off = 1; off < 64; off <<= 1) {
        int n = __shfl_up(sum, off);
        if (lane >= off) sum += n;
    }
    if (lane == 63) wsum[w] = sum;
    __syncthreads();
    int woff = 0;
    for (int i = 0; i < w; ++i) woff += wsum[i];
    int toff = woff + (sum - tl);
#pragma unroll
    for (int u = 0; u < 8; ++u) {
        int idx = base + u;
        if (idx < N) start[idx] = toff + ex[u];
    }
    if (t == 255) bsum[blockIdx.x] = woff + sum;
}

__global__ void scan_top_kernel(int* __restrict__ bsum, int NB) {
    int t = threadIdx.x;
    if (NB <= 64) {
        int v = (t < NB) ? bsum[t] : 0;
        int sum = v;
#pragma unroll
        for (int off = 1; off < 64; off <<= 1) {
            int n = __shfl_up(sum, off);
            if (t >= off) sum += n;
        }
        if (t < NB) bsum[t] = sum - v;
    } else if (t == 0) {
        int a = 0;
        for (int i = 0; i < NB; ++i) { int v = bsum[i]; bsum[i] = a; a += v; }
    }
}

__global__ void scan_add_kernel(int* __restrict__ start, int* __restrict__ cursor,
        const int* __restrict__ bsum, const int* __restrict__ deg,
        float* __restrict__ dinv, int N) {
    int i = blockIdx.x * blockDim.x + threadIdx.x;
    if (i >= N) return;
    int s = start[i] + bsum[i / SCAN_CHUNK];
    start[i] = s;
    cursor[i] = s;
    dinv[i] = rsqrtf((float)(deg[i] + 1));  // +1 self loop
}

// ---------------- bin edges by dst: ssrc holds src indices grouped by dst ----------------
__global__ void bin_kernel(const int* __restrict__ rowi, const int* __restrict__ coli,
        int* __restrict__ cursor, int* __restrict__ ssrc, int E) {
    int e = blockIdx.x * blockDim.x + threadIdx.x;
    if (e >= E) return;
    int r = rowi[e], c = coli[e];
    int p = atomicAdd(&cursor[c], 1);
    ssrc[p] = r;
}

// ---------------- layer-1 GEMM: hs[r,f] = dinv[r] * sum_k x[r,k]*W1[k,f] ----------------
__global__ __launch_bounds__(256) void gemm1_kernel(
    const float* __restrict__ x, const float* __restrict__ W1,
    const float* __restrict__ dinv, float* __restrict__ hs, int N) {
    __shared__ __align__(16) float wsT[F1][XPAD];   // wsT[f][k] = W1[k][f]
    __shared__ __align__(16) float xs[16][XPAD];    // 16 rows of x, padded stride
    int t = threadIdx.x;
    for (int i = t; i < N_FEAT * F1; i += 256) {
        int k = i >> 4, f = i & 15;
        wsT[f][k] = W1[i];
    }
    int row0 = blockIdx.x * 16;
    for (int i = t; i < 16 * (N_FEAT / 4); i += 256) {
        int r = i >> 5, k4 = i & 31;
        int row = row0 + r;
        float4 v = (row < N) ? ((const float4*)(x + (size_t)row * N_FEAT))[k4]
                             : make_float4(0.f, 0.f, 0.f, 0.f);
        *(float4*)&xs[r][k4 * 4] = v;
    }
    __syncthreads();
    int rr = t >> 4, f = t & 15;
    int row = row0 + rr;
    if (row >= N) return;
    float acc = 0.f;
#pragma unroll
    for (int k4 = 0; k4 < 32; ++k4) {
        float4 xv = *(const float4*)&xs[rr][k4 * 4];
        float4 wv = *(const float4*)&wsT[f][k4 * 4];
        acc += xv.x * wv.x + xv.y * wv.y + xv.z * wv.z + xv.w * wv.w;
    }
    hs[(size_t)row * F1 + f] = acc * dinv[row];
}

// ------- layer-1 aggregate (gather) + bias + relu + GEMM2, 4 lanes/node, float4/lane -------
__global__ __launch_bounds__(256) void aggregate1_kernel(
    const int* __restrict__ start, const int* __restrict__ deg,
    const int* __restrict__ ssrc, const float* __restrict__ hs,
    const float* __restrict__ dinv, const float* __restrict__ b1,
    const float* __restrict__ W2, float* __restrict__ hs2, int N) {
    int t = blockIdx.x * 256 + threadIdx.x;
    int g = t >> 2;       // node
    int cl = t & 3;       // feature quad: f = 4*cl + u
    if (g >= N) return;
    const float4* hs4 = (const float4*)hs;
    float4 acc = hs4[(size_t)g * 4 + cl];   // self loop contribution
    int s = start[g], d = deg[g];
    int k = 0;
    for (; k + 1 < d; k += 2) {
        int s0 = ssrc[s + k], s1 = ssrc[s + k + 1];
        float4 a = hs4[(size_t)s0 * 4 + cl];
        float4 b = hs4[(size_t)s1 * 4 + cl];
        acc.x += a.x + b.x; acc.y += a.y + b.y;
        acc.z += a.z + b.z; acc.w += a.w + b.w;
    }
    if (k < d) {
        float4 a = hs4[(size_t)ssrc[s + k] * 4 + cl];
        acc.x += a.x; acc.y += a.y; acc.z += a.z; acc.w += a.w;
    }
    float di = dinv[g];
    int f0 = cl * 4;
    float o0 = fmaxf(di * acc.x + b1[f0 + 0], 0.f);
    float o1 = fmaxf(di * acc.y + b1[f0 + 1], 0.f);
    float o2 = fmaxf(di * acc.z + b1[f0 + 2], 0.f);
    float o3 = fmaxf(di * acc.w + b1[f0 + 3], 0.f);
    float v0 = o0 * W2[(f0 + 0) * F2 + 0] + o1 * W2[(f0 + 1) * F2 + 0]
             + o2 * W2[(f0 + 2) * F2 + 0] + o3 * W2[(f0 + 3) * F2 + 0];
    float v1 = o0 * W2[(f0 + 0) * F2 + 1] + o1 * W2[(f0 + 1) * F2 + 1]
             + o2 * W2[(f0 + 2) * F2 + 1] + o3 * W2[(f0 + 3) * F2 + 1];
    v0 += __shfl_xor(v0, 1); v0 += __shfl_xor(v0, 2);
    v1 += __shfl_xor(v1, 1); v1 += __shfl_xor(v1, 2);
    if (cl == 0) *(float2*)&hs2[(size_t)g * 2] = make_float2(di * v0, di * v1);
}

// ------- layer-2 aggregate (gather) + finalize: out = dinv*(sum + self) + b2 -------
__global__ __launch_bounds__(256) void aggregate2_kernel(
    const int* __restrict__ start, const int* __restrict__ deg,
    const int* __restrict__ ssrc, const float* __restrict__ hs2,
    const float* __restrict__ dinv, const float* __restrict__ b2,
    float* __restrict__ out, int N) {
    int t = blockIdx.x * 256 + threadIdx.x;
    int g = t >> 2;
    int l = t & 3;
    if (g >= N) return;
    int j = l & 1, c = l >> 1;          // feature j, chunk c (2 chunks)
    int s = start[g], d = deg[g];
    float acc = 0.f;
    for (int k = c; k < d; k += 2)
        acc += hs2[(size_t)ssrc[s + k] * 2 + j];
    acc += __shfl_xor(acc, 2);          // combine the two chunks per feature
    if (l < 2)
        out[(size_t)g * 2 + j] = dinv[g] * (acc + hs2[(size_t)g * 2 + j]) + b2[j];
}

extern "C" void kernel_launch(void* const* d_in, const int* in_sizes, int n_in,
                              void* d_out, int out_size, void* d_ws, size_t ws_size,
                              hipStream_t stream) {
    const float* x  = (const float*)d_in[0];
    const int*   ei = (const int*)d_in[1];
    const float* W1 = (const float*)d_in[2];
    const float* b1 = (const float*)d_in[3];
    const float* W2 = (const float*)d_in[4];
    const float* b2 = (const float*)d_in[5];
    int N = in_sizes[0] / N_FEAT;
    int E = in_sizes[1] / 2;
    const int* rowi = ei;        // edge_index[0] = src
    const int* coli = ei + E;    // edge_index[1] = dst
    float* out = (float*)d_out;

    // workspace layout (4B units), regions padded to 1024-elem alignment
    size_t NP = ((size_t)N + 1023) & ~(size_t)1023;
    int*   wsI    = (int*)d_ws;
    int*   deg    = wsI;                         // NP
    int*   start  = wsI + NP;                    // NP
    int*   cursor = wsI + 2 * NP;                // NP
    int*   bsum   = wsI + 3 * NP;                // 1024
    float* dinv   = (float*)(wsI + 3 * NP + 1024); // NP
    float* hs     = dinv + NP;                   // 16*NP
    float* hs2    = hs + 16 * NP;                // 2*NP
    int*   ssrc   = (int*)(hs2 + 2 * NP);        // E

    int NB = (N + SCAN_CHUNK - 1) / SCAN_CHUNK;

    hipMemsetAsync(deg, 0, (size_t)N * sizeof(int), stream);

    deg_kernel<<<((E + 3) / 4 + 255) / 256, 256, 0, stream>>>(coli, E, deg);
    scan_blocks_kernel<<<NB, 256, 0, stream>>>(deg, start, bsum, N);
    scan_top_kernel<<<1, 64, 0, stream>>>(bsum, NB);
    scan_add_kernel<<<(N + 255) / 256, 256, 0, stream>>>(start, cursor, bsum, deg, dinv, N);
    bin_kernel<<<(E + 255) / 256, 256, 0, stream>>>(rowi, coli, cursor, ssrc, E);

    gemm1_kernel<<<(N + 15) / 16, 256, 0, stream>>>(x, W1, dinv, hs, N);

    aggregate1_kernel<<<((size_t)N * 4 + 255) / 256, 256, 0, stream>>>(
        start, deg, ssrc, hs, dinv, b1, W2, hs2, N);
    aggregate2_kernel<<<((size_t)N * 4 + 255) / 256, 256, 0, stream>>>(
        start, deg, ssrc, hs2, dinv, b2, out, N);
}